// Round 6
// baseline (302.537 us; speedup 1.0000x reference)
//
#include <hip/hip_runtime.h>
#include <math.h>

typedef _Float16 half8   __attribute__((ext_vector_type(8)));
typedef float    float4v __attribute__((ext_vector_type(4)));

constexpr int T_ = 1 << 18;            // hash table size per level
constexpr unsigned TMASK = T_ - 1;
constexpr unsigned PRIME = 2654435761u;
constexpr int HP = 72;                 // H row pitch in f16 (64 + 8 pad)

// ws layout:
//   [0, 22528)      : 22 W-fragments (f16), 64 lanes x 8 halfs each
//   [22528, 23360)  : biases fp32: b1[64] b2[64] b3[64] b4pad[16]
//   [23360, 23424)  : N_values fp32 [16]
constexpr int WFRAG_HALFS = 22 * 64 * 8;
constexpr int BIAS_FLOATS = 208;
constexpr int WS_BYTES    = 22528 + (BIAS_FLOATS + 16) * 4;  // 23424
constexpr int WS_UINT4    = WS_BYTES / 16;                   // 1464

struct NVals { float n[16]; };

// ---------------- prep: swizzle weights into MFMA fragment order ----------------
__global__ void prep_weights(const float* __restrict__ W1, const float* __restrict__ b1,
                             const float* __restrict__ W2, const float* __restrict__ b2,
                             const float* __restrict__ W3, const float* __restrict__ b3,
                             const float* __restrict__ W4, const float* __restrict__ b4,
                             _Float16* __restrict__ wsW, float* __restrict__ wsB, NVals nv)
{
    const int tid = threadIdx.x;
    // weights-as-A (transposed form): lane l holds W[k=32s+8*(l>>4)+j][n=16t+(l&15)]
    for (int e = tid; e < WFRAG_HALFS; e += 256) {
        const int frag = e >> 9;
        const int l    = (e >> 3) & 63;
        const int j    = e & 7;
        const int g = l >> 4, m = l & 15;
        float v;
        if (frag < 4) {
            v = W1[(8*g + j) * 64 + 16*frag + m];
        } else if (frag < 12) {
            const int s = (frag - 4) >> 2, t = (frag - 4) & 3;
            v = W2[(32*s + 8*g + j) * 64 + 16*t + m];
        } else if (frag < 20) {
            const int s = (frag - 12) >> 2, t = (frag - 12) & 3;
            v = W3[(32*s + 8*g + j) * 64 + 16*t + m];
        } else {
            const int s = frag - 20;
            v = (m < 3) ? W4[(32*s + 8*g + j) * 3 + m] : 0.f;
        }
        wsW[e] = (_Float16)v;
    }
    if (tid < 64) { wsB[tid] = b1[tid]; wsB[64 + tid] = b2[tid]; wsB[128 + tid] = b3[tid]; }
    if (tid >= 64 && tid < 80) { const int r = tid - 64; wsB[192 + r] = (r < 3) ? b4[r] : 0.f; }
    if (tid >= 80 && tid < 96)  wsB[BIAS_FLOATS + (tid - 80)] = nv.n[tid - 80];
}

// ---------------- main fused kernel ----------------
// Block = 256 = 4 waves; wave does 4 tiles of 16 points. Transposed MFMA form
// (activations = B-operand, weights = A). Round-6 changes vs round-4:
//  * depth-1 gather prefetch: iter it+1's 12 divergent loads are issued BEFORE
//    iter it's DS fences (the "memory"-clobber fences otherwise pin them after),
//    so gather latency is covered by the ~900-cyc MLP chain of the prior tile.
//  * subtable dropped (round-5: FETCH unchanged, dur unchanged -> it bought
//    nothing and cost occupancy). LDS back to ~32 KB.
//  * __launch_bounds__(256,4): target 4 blocks/CU (16 waves), VGPR cap 128.
#define DS_FENCE() __asm__ volatile("s_waitcnt lgkmcnt(0)" ::: "memory")

__global__ __launch_bounds__(256, 4)
void fused_hashnerf_mfma(const float2* __restrict__ X,
                         const float2* __restrict__ table,
                         const uint4* __restrict__ ws,
                         float* __restrict__ out)
{
    __shared__ uint4    sRaw[WS_UINT4];
    __shared__ _Float16 sH[4][16 * HP];

    const int tid = threadIdx.x;
    for (int i = tid; i < WS_UINT4; i += 256) sRaw[i] = ws[i];
    __syncthreads();

    const _Float16* Wl = (const _Float16*)sRaw;
    const float*    Bl = (const float*)(sRaw + (22528 / 16));

    const int wave = tid >> 6, lane = tid & 63;
    const int g = lane >> 4, c = lane & 15;
    _Float16* H = &sH[wave][0];

    float4v b1f[4], b2f[4], b3f[4], b4f;
    #pragma unroll
    for (int t = 0; t < 4; ++t) {
        b1f[t] = *(const float4v*)(Bl +       16*t + 4*g);
        b2f[t] = *(const float4v*)(Bl +  64 + 16*t + 4*g);
        b3f[t] = *(const float4v*)(Bl + 128 + 16*t + 4*g);
    }
    b4f = *(const float4v*)(Bl + 192 + 4*g);

    // per-lane level constants (levels 4g..4g+3)
    float nvq[4]; const float2* tq[4]; float v0x[4], v0y[4];
    #pragma unroll
    for (int q = 0; q < 4; ++q) {
        nvq[q] = Bl[BIAS_FLOATS + 4*g + q];
        tq[q]  = table + (size_t)(4*g + q) * T_;
        const float2 v0 = tq[q][0];          // corner (0,0): point-invariant
        v0x[q] = v0.x; v0y[q] = v0.y;
    }

    const int base_pt = blockIdx.x * 256 + wave * 64;

    // all 4 point coords up front (coalesced, broadcast across g-groups)
    float2 xy[4];
    #pragma unroll
    for (int it = 0; it < 4; ++it) xy[it] = X[base_pt + it * 16 + c];

    // gather slot (live across the MLP of the previous iter)
    float2 s1[4], s3[4], s2[4];

    auto issue_gathers = [&](const float2 p) {
        #pragma unroll
        for (int q = 0; q < 4; ++q) {
            const float n = nvq[q];
            const unsigned xi = (unsigned)(int)floorf(p.x * n);
            const unsigned yi = (unsigned)(int)floorf(p.y * n);
            const unsigned yp = yi * PRIME;
            s1[q] = tq[q][yp & TMASK];         // corner (0, yf)
            s3[q] = tq[q][(xi ^ yp) & TMASK];  // corner (xf, yf)
            s2[q] = tq[q][xi & TMASK];         // corner (xf, 0)
        }
    };

    issue_gathers(xy[0]);

    #pragma unroll
    for (int it = 0; it < 4; ++it) {
        const int p = base_pt + it * 16 + c;

        // ---- blend slot -> B-fragment (recompute fx/fy: cheap VALU) ----
        half8 feat;
        #pragma unroll
        for (int q = 0; q < 4; ++q) {
            const float n = nvq[q];
            const float xs = xy[it].x * n, ys = xy[it].y * n;
            const float fx = xs - floorf(xs), fy = ys - floorf(ys);
            const float cx = 1.f - fx, cy = 1.f - fy;
            const float w0 = cx*cy, w1 = cx*fy, w2 = fx*cy, w3 = fx*fy;
            feat[2*q+0] = (_Float16)(w0*v0x[q] + w1*s1[q].x + w2*s2[q].x + w3*s3[q].x);
            feat[2*q+1] = (_Float16)(w0*v0y[q] + w1*s1[q].y + w2*s2[q].y + w3*s3[q].y);
        }

        // ---- prefetch next tile's gathers BEFORE any fence ----
        if (it < 3) issue_gathers(xy[it + 1]);

        // ---- L1 ----
        float4v acc[4];
        #pragma unroll
        for (int t = 0; t < 4; ++t) {
            const half8 wf = *(const half8*)(Wl + (t*64 + lane)*8);
            acc[t] = __builtin_amdgcn_mfma_f32_16x16x32_f16(wf, feat, b1f[t], 0, 0, 0);
        }
        #pragma unroll
        for (int t = 0; t < 4; ++t) {
            union { _Float16 h[4]; float2 f2; } u;
            #pragma unroll
            for (int r = 0; r < 4; ++r) {
                const float v = acc[t][r];
                u.h[r] = (_Float16)(v > 0.f ? v : 0.01f * v);
            }
            *(float2*)(H + c*HP + 16*t + 4*g) = u.f2;
        }
        DS_FENCE();

        // ---- L2 ----
        half8 a0 = *(const half8*)(H + c*HP +      8*g);
        half8 a1 = *(const half8*)(H + c*HP + 32 + 8*g);
        float4v acc2[4];
        #pragma unroll
        for (int t = 0; t < 4; ++t) {
            const half8 w0f = *(const half8*)(Wl + ((4 + t)*64 + lane)*8);
            const half8 w1f = *(const half8*)(Wl + ((8 + t)*64 + lane)*8);
            float4v a = __builtin_amdgcn_mfma_f32_16x16x32_f16(w0f, a0, b2f[t], 0, 0, 0);
            acc2[t]   = __builtin_amdgcn_mfma_f32_16x16x32_f16(w1f, a1, a,      0, 0, 0);
        }
        #pragma unroll
        for (int t = 0; t < 4; ++t) {
            union { _Float16 h[4]; float2 f2; } u;
            #pragma unroll
            for (int r = 0; r < 4; ++r) {
                const float v = acc2[t][r];
                u.h[r] = (_Float16)(v > 0.f ? v : 0.01f * v);
            }
            *(float2*)(H + c*HP + 16*t + 4*g) = u.f2;
        }
        DS_FENCE();

        // ---- L3 ----
        a0 = *(const half8*)(H + c*HP +      8*g);
        a1 = *(const half8*)(H + c*HP + 32 + 8*g);
        float4v acc3[4];
        #pragma unroll
        for (int t = 0; t < 4; ++t) {
            const half8 w0f = *(const half8*)(Wl + ((12 + t)*64 + lane)*8);
            const half8 w1f = *(const half8*)(Wl + ((16 + t)*64 + lane)*8);
            float4v a = __builtin_amdgcn_mfma_f32_16x16x32_f16(w0f, a0, b3f[t], 0, 0, 0);
            acc3[t]   = __builtin_amdgcn_mfma_f32_16x16x32_f16(w1f, a1, a,      0, 0, 0);
        }
        #pragma unroll
        for (int t = 0; t < 4; ++t) {
            union { _Float16 h[4]; float2 f2; } u;
            #pragma unroll
            for (int r = 0; r < 4; ++r) {
                const float v = acc3[t][r];
                u.h[r] = (_Float16)(v > 0.f ? v : 0.01f * v);
            }
            *(float2*)(H + c*HP + 16*t + 4*g) = u.f2;
        }
        DS_FENCE();

        // ---- L4 ----
        a0 = *(const half8*)(H + c*HP +      8*g);
        a1 = *(const half8*)(H + c*HP + 32 + 8*g);
        const half8 w40 = *(const half8*)(Wl + (20*64 + lane)*8);
        const half8 w41 = *(const half8*)(Wl + (21*64 + lane)*8);
        float4v o = __builtin_amdgcn_mfma_f32_16x16x32_f16(w40, a0, b4f, 0, 0, 0);
        o         = __builtin_amdgcn_mfma_f32_16x16x32_f16(w41, a1, o,   0, 0, 0);
        if (g == 0) {
            float* op = out + (size_t)3 * p;
            op[0] = fmaxf(o[0], 0.f);
            op[1] = fmaxf(o[1], 0.f);
            op[2] = fmaxf(o[2], 0.f);
        }
    }
}

extern "C" void kernel_launch(void* const* d_in, const int* in_sizes, int n_in,
                              void* d_out, int out_size, void* d_ws, size_t ws_size,
                              hipStream_t stream) {
    const float2* X     = (const float2*)d_in[0];
    const float2* table = (const float2*)d_in[1];
    const float*  W1    = (const float*)d_in[2];
    const float*  b1    = (const float*)d_in[3];
    const float*  W2    = (const float*)d_in[4];
    const float*  b2    = (const float*)d_in[5];
    const float*  W3    = (const float*)d_in[6];
    const float*  b3    = (const float*)d_in[7];
    const float*  W4    = (const float*)d_in[8];
    const float*  b4    = (const float*)d_in[9];
    float* out          = (float*)d_out;

    const int npts = in_sizes[0] / 2;

    // N_l = floor(float32(16 * b^l)), b in double (matches numpy)
    NVals nv;
    const double bg = exp((log(1024.0) - log(16.0)) / 15.0);
    for (int l = 0; l < 16; ++l)
        nv.n[l] = floorf((float)(16.0 * pow(bg, (double)l)));

    _Float16* wsW = (_Float16*)d_ws;
    float*    wsB = (float*)((char*)d_ws + 22528);

    prep_weights<<<1, 256, 0, stream>>>(W1, b1, W2, b2, W3, b3, W4, b4, wsW, wsB, nv);
    fused_hashnerf_mfma<<<npts / 256, 256, 0, stream>>>(X, table, (const uint4*)d_ws, out);
}

// Round 7
// 289.331 us; speedup vs baseline: 1.0456x; 1.0456x over previous
//
#include <hip/hip_runtime.h>
#include <math.h>

typedef _Float16 half8   __attribute__((ext_vector_type(8)));
typedef float    float4v __attribute__((ext_vector_type(4)));

constexpr int T_ = 1 << 18;            // hash table size per level
constexpr unsigned TMASK = T_ - 1;
constexpr unsigned PRIME = 2654435761u;
constexpr int HP = 72;                 // H row pitch in f16 (64 + 8 pad)

// ws layout:
//   [0, 22528)      : 22 W-fragments (f16), 64 lanes x 8 halfs each
//   [22528, 23360)  : biases fp32: b1[64] b2[64] b3[64] b4pad[16]
//   [23360, 23424)  : N_values fp32 [16]
constexpr int WFRAG_HALFS = 22 * 64 * 8;
constexpr int BIAS_FLOATS = 208;
constexpr int WS_BYTES    = 22528 + (BIAS_FLOATS + 16) * 4;  // 23424
constexpr int WS_UINT4    = WS_BYTES / 16;                   // 1464

struct NVals { float n[16]; };

// ---------------- prep: swizzle weights into MFMA fragment order ----------------
__global__ void prep_weights(const float* __restrict__ W1, const float* __restrict__ b1,
                             const float* __restrict__ W2, const float* __restrict__ b2,
                             const float* __restrict__ W3, const float* __restrict__ b3,
                             const float* __restrict__ W4, const float* __restrict__ b4,
                             _Float16* __restrict__ wsW, float* __restrict__ wsB, NVals nv)
{
    const int tid = threadIdx.x;
    // weights-as-A (transposed form): lane l holds W[k=32s+8*(l>>4)+j][n=16t+(l&15)]
    for (int e = tid; e < WFRAG_HALFS; e += 256) {
        const int frag = e >> 9;
        const int l    = (e >> 3) & 63;
        const int j    = e & 7;
        const int g = l >> 4, m = l & 15;
        float v;
        if (frag < 4) {
            v = W1[(8*g + j) * 64 + 16*frag + m];
        } else if (frag < 12) {
            const int s = (frag - 4) >> 2, t = (frag - 4) & 3;
            v = W2[(32*s + 8*g + j) * 64 + 16*t + m];
        } else if (frag < 20) {
            const int s = (frag - 12) >> 2, t = (frag - 12) & 3;
            v = W3[(32*s + 8*g + j) * 64 + 16*t + m];
        } else {
            const int s = frag - 20;
            v = (m < 3) ? W4[(32*s + 8*g + j) * 3 + m] : 0.f;
        }
        wsW[e] = (_Float16)v;
    }
    if (tid < 64) { wsB[tid] = b1[tid]; wsB[64 + tid] = b2[tid]; wsB[128 + tid] = b3[tid]; }
    if (tid >= 64 && tid < 80) { const int r = tid - 64; wsB[192 + r] = (r < 3) ? b4[r] : 0.f; }
    if (tid >= 80 && tid < 96)  wsB[BIAS_FLOATS + (tid - 80)] = nv.n[tid - 80];
}

// ---------------- main fused kernel ----------------
// Block = 256 = 4 waves; each wave: 2 PAIRS of 16-pt tiles (64 pts). Transposed
// MFMA (activations = B-operand). Round-7: two tiles ride the MLP together ->
// 2x independent MFMA/LDS streams between fences, half the fences per point,
// weight fragments shared across both tiles, next pair's 24 gathers issued
// before the current pair's fences. __launch_bounds__(256,2): 256-VGPR cap so
// the gather slots CANNOT spill (round-6 regression: (256,4) spilled them ->
// WRITE 62.8 MB).
#define DS_FENCE() __asm__ volatile("s_waitcnt lgkmcnt(0)" ::: "memory")

__global__ __launch_bounds__(256, 2)
void fused_hashnerf_mfma(const float2* __restrict__ X,
                         const float2* __restrict__ table,
                         const uint4* __restrict__ ws,
                         float* __restrict__ out)
{
    __shared__ uint4    sRaw[WS_UINT4];
    __shared__ _Float16 sH[4][2][16 * HP];   // [wave][tile-slot][...]

    const int tid = threadIdx.x;
    for (int i = tid; i < WS_UINT4; i += 256) sRaw[i] = ws[i];
    __syncthreads();

    const _Float16* Wl = (const _Float16*)sRaw;
    const float*    Bl = (const float*)(sRaw + (22528 / 16));

    const int wave = tid >> 6, lane = tid & 63;
    const int g = lane >> 4, c = lane & 15;
    _Float16* HA = &sH[wave][0][0];
    _Float16* HB = &sH[wave][1][0];

    float4v b1f[4], b2f[4], b3f[4], b4f;
    #pragma unroll
    for (int t = 0; t < 4; ++t) {
        b1f[t] = *(const float4v*)(Bl +       16*t + 4*g);
        b2f[t] = *(const float4v*)(Bl +  64 + 16*t + 4*g);
        b3f[t] = *(const float4v*)(Bl + 128 + 16*t + 4*g);
    }
    b4f = *(const float4v*)(Bl + 192 + 4*g);

    // per-lane level constants (levels 4g..4g+3)
    float nvq[4]; const float2* tq[4]; float v0x[4], v0y[4];
    #pragma unroll
    for (int q = 0; q < 4; ++q) {
        nvq[q] = Bl[BIAS_FLOATS + 4*g + q];
        tq[q]  = table + (size_t)(4*g + q) * T_;
        const float2 v0 = tq[q][0];          // corner (0,0): point-invariant
        v0x[q] = v0.x; v0y[q] = v0.y;
    }

    const int base_pt = blockIdx.x * 256 + wave * 64;

    float2 xy[4];
    #pragma unroll
    for (int it = 0; it < 4; ++it) xy[it] = X[base_pt + it * 16 + c];

    // gather slots for the two in-flight tiles
    float2 sA1[4], sA3[4], sA2[4];
    float2 sB1[4], sB3[4], sB2[4];

    auto issue = [&](const float2 p, float2 (&s1)[4], float2 (&s3)[4], float2 (&s2)[4]) {
        #pragma unroll
        for (int q = 0; q < 4; ++q) {
            const float n = nvq[q];
            const unsigned xi = (unsigned)(int)floorf(p.x * n);
            const unsigned yi = (unsigned)(int)floorf(p.y * n);
            const unsigned yp = yi * PRIME;
            s1[q] = tq[q][yp & TMASK];         // corner (0, yf)
            s3[q] = tq[q][(xi ^ yp) & TMASK];  // corner (xf, yf)
            s2[q] = tq[q][xi & TMASK];         // corner (xf, 0)
        }
    };
    auto blend = [&](const float2 p, const float2 (&s1)[4], const float2 (&s3)[4],
                     const float2 (&s2)[4]) -> half8 {
        half8 f;
        #pragma unroll
        for (int q = 0; q < 4; ++q) {
            const float n = nvq[q];
            const float xs = p.x * n, ys = p.y * n;
            const float fx = xs - floorf(xs), fy = ys - floorf(ys);
            const float cx = 1.f - fx, cy = 1.f - fy;
            const float w0 = cx*cy, w1 = cx*fy, w2 = fx*cy, w3 = fx*fy;
            f[2*q+0] = (_Float16)(w0*v0x[q] + w1*s1[q].x + w2*s2[q].x + w3*s3[q].x);
            f[2*q+1] = (_Float16)(w0*v0y[q] + w1*s1[q].y + w2*s2[q].y + w3*s3[q].y);
        }
        return f;
    };
    auto store_act = [&](_Float16* H, const float4v (&acc)[4]) {
        #pragma unroll
        for (int t = 0; t < 4; ++t) {
            union { _Float16 h[4]; float2 f2; } u;
            #pragma unroll
            for (int r = 0; r < 4; ++r) {
                const float v = acc[t][r];
                u.h[r] = (_Float16)(v > 0.f ? v : 0.01f * v);
            }
            *(float2*)(H + c*HP + 16*t + 4*g) = u.f2;
        }
    };

    issue(xy[0], sA1, sA3, sA2);
    issue(xy[1], sB1, sB3, sB2);

    #pragma unroll
    for (int j = 0; j < 2; ++j) {
        const int pA = base_pt + (2*j + 0) * 16 + c;
        const int pB = base_pt + (2*j + 1) * 16 + c;

        const half8 fA = blend(xy[2*j + 0], sA1, sA3, sA2);
        const half8 fB = blend(xy[2*j + 1], sB1, sB3, sB2);

        // next pair's gathers: in flight across this pair's whole MLP
        if (j == 0) {
            issue(xy[2], sA1, sA3, sA2);
            issue(xy[3], sB1, sB3, sB2);
        }

        // ---- L1 (8 MFMA, shared weight frags) ----
        float4v aA[4], aB[4];
        #pragma unroll
        for (int t = 0; t < 4; ++t) {
            const half8 wf = *(const half8*)(Wl + (t*64 + lane)*8);
            aA[t] = __builtin_amdgcn_mfma_f32_16x16x32_f16(wf, fA, b1f[t], 0, 0, 0);
            aB[t] = __builtin_amdgcn_mfma_f32_16x16x32_f16(wf, fB, b1f[t], 0, 0, 0);
        }
        store_act(HA, aA); store_act(HB, aB);
        DS_FENCE();

        // ---- L2 (16 MFMA) ----
        half8 a0A = *(const half8*)(HA + c*HP +      8*g);
        half8 a1A = *(const half8*)(HA + c*HP + 32 + 8*g);
        half8 a0B = *(const half8*)(HB + c*HP +      8*g);
        half8 a1B = *(const half8*)(HB + c*HP + 32 + 8*g);
        float4v cA[4], cB[4];
        #pragma unroll
        for (int t = 0; t < 4; ++t) {
            const half8 w0f = *(const half8*)(Wl + ((4 + t)*64 + lane)*8);
            const half8 w1f = *(const half8*)(Wl + ((8 + t)*64 + lane)*8);
            float4v x;
            x     = __builtin_amdgcn_mfma_f32_16x16x32_f16(w0f, a0A, b2f[t], 0, 0, 0);
            cA[t] = __builtin_amdgcn_mfma_f32_16x16x32_f16(w1f, a1A, x,      0, 0, 0);
            x     = __builtin_amdgcn_mfma_f32_16x16x32_f16(w0f, a0B, b2f[t], 0, 0, 0);
            cB[t] = __builtin_amdgcn_mfma_f32_16x16x32_f16(w1f, a1B, x,      0, 0, 0);
        }
        store_act(HA, cA); store_act(HB, cB);
        DS_FENCE();

        // ---- L3 (16 MFMA) ----
        a0A = *(const half8*)(HA + c*HP +      8*g);
        a1A = *(const half8*)(HA + c*HP + 32 + 8*g);
        a0B = *(const half8*)(HB + c*HP +      8*g);
        a1B = *(const half8*)(HB + c*HP + 32 + 8*g);
        #pragma unroll
        for (int t = 0; t < 4; ++t) {
            const half8 w0f = *(const half8*)(Wl + ((12 + t)*64 + lane)*8);
            const half8 w1f = *(const half8*)(Wl + ((16 + t)*64 + lane)*8);
            float4v x;
            x     = __builtin_amdgcn_mfma_f32_16x16x32_f16(w0f, a0A, b3f[t], 0, 0, 0);
            cA[t] = __builtin_amdgcn_mfma_f32_16x16x32_f16(w1f, a1A, x,      0, 0, 0);
            x     = __builtin_amdgcn_mfma_f32_16x16x32_f16(w0f, a0B, b3f[t], 0, 0, 0);
            cB[t] = __builtin_amdgcn_mfma_f32_16x16x32_f16(w1f, a1B, x,      0, 0, 0);
        }
        store_act(HA, cA); store_act(HB, cB);
        DS_FENCE();

        // ---- L4 (4 MFMA) ----
        a0A = *(const half8*)(HA + c*HP +      8*g);
        a1A = *(const half8*)(HA + c*HP + 32 + 8*g);
        a0B = *(const half8*)(HB + c*HP +      8*g);
        a1B = *(const half8*)(HB + c*HP + 32 + 8*g);
        const half8 w40 = *(const half8*)(Wl + (20*64 + lane)*8);
        const half8 w41 = *(const half8*)(Wl + (21*64 + lane)*8);
        float4v oA = __builtin_amdgcn_mfma_f32_16x16x32_f16(w40, a0A, b4f, 0, 0, 0);
        oA         = __builtin_amdgcn_mfma_f32_16x16x32_f16(w41, a1A, oA,  0, 0, 0);
        float4v oB = __builtin_amdgcn_mfma_f32_16x16x32_f16(w40, a0B, b4f, 0, 0, 0);
        oB         = __builtin_amdgcn_mfma_f32_16x16x32_f16(w41, a1B, oB,  0, 0, 0);
        if (g == 0) {
            float* opA = out + (size_t)3 * pA;
            opA[0] = fmaxf(oA[0], 0.f); opA[1] = fmaxf(oA[1], 0.f); opA[2] = fmaxf(oA[2], 0.f);
            float* opB = out + (size_t)3 * pB;
            opB[0] = fmaxf(oB[0], 0.f); opB[1] = fmaxf(oB[1], 0.f); opB[2] = fmaxf(oB[2], 0.f);
        }
    }
}

extern "C" void kernel_launch(void* const* d_in, const int* in_sizes, int n_in,
                              void* d_out, int out_size, void* d_ws, size_t ws_size,
                              hipStream_t stream) {
    const float2* X     = (const float2*)d_in[0];
    const float2* table = (const float2*)d_in[1];
    const float*  W1    = (const float*)d_in[2];
    const float*  b1    = (const float*)d_in[3];
    const float*  W2    = (const float*)d_in[4];
    const float*  b2    = (const float*)d_in[5];
    const float*  W3    = (const float*)d_in[6];
    const float*  b3    = (const float*)d_in[7];
    const float*  W4    = (const float*)d_in[8];
    const float*  b4    = (const float*)d_in[9];
    float* out          = (float*)d_out;

    const int npts = in_sizes[0] / 2;

    // N_l = floor(float32(16 * b^l)), b in double (matches numpy)
    NVals nv;
    const double bg = exp((log(1024.0) - log(16.0)) / 15.0);
    for (int l = 0; l < 16; ++l)
        nv.n[l] = floorf((float)(16.0 * pow(bg, (double)l)));

    _Float16* wsW = (_Float16*)d_ws;
    float*    wsB = (float*)((char*)d_ws + 22528);

    prep_weights<<<1, 256, 0, stream>>>(W1, b1, W2, b2, W3, b3, W4, b4, wsW, wsB, nv);
    fused_hashnerf_mfma<<<npts / 256, 256, 0, stream>>>(X, table, (const uint4*)d_ws, out);
}

// Round 8
// 283.311 us; speedup vs baseline: 1.0679x; 1.0212x over previous
//
#include <hip/hip_runtime.h>
#include <math.h>

typedef _Float16 half8   __attribute__((ext_vector_type(8)));
typedef float    float4v __attribute__((ext_vector_type(4)));

constexpr int T_ = 1 << 18;            // hash table size per level
constexpr unsigned TMASK = T_ - 1;
constexpr unsigned PRIME = 2654435761u;
constexpr int HP = 72;                 // H row pitch in f16 (64 + 8 pad)

// ws layout:
//   [0, 22528)      : 22 W-fragments (f16), 64 lanes x 8 halfs each
//   [22528, 23360)  : biases fp32: b1[64] b2[64] b3[64] b4pad[16]
//   [23360, 23424)  : N_values fp32 [16]
constexpr int WFRAG_HALFS = 22 * 64 * 8;
constexpr int BIAS_FLOATS = 208;
constexpr int WS_BYTES    = 22528 + (BIAS_FLOATS + 16) * 4;  // 23424
constexpr int WS_UINT4    = WS_BYTES / 16;                   // 1464

struct NVals { float n[16]; };

// ---------------- prep: swizzle weights into MFMA fragment order ----------------
__global__ void prep_weights(const float* __restrict__ W1, const float* __restrict__ b1,
                             const float* __restrict__ W2, const float* __restrict__ b2,
                             const float* __restrict__ W3, const float* __restrict__ b3,
                             const float* __restrict__ W4, const float* __restrict__ b4,
                             _Float16* __restrict__ wsW, float* __restrict__ wsB, NVals nv)
{
    const int tid = threadIdx.x;
    // weights-as-A (transposed form): lane l holds W[k=32s+8*(l>>4)+j][n=16t+(l&15)]
    for (int e = tid; e < WFRAG_HALFS; e += 256) {
        const int frag = e >> 9;
        const int l    = (e >> 3) & 63;
        const int j    = e & 7;
        const int g = l >> 4, m = l & 15;
        float v;
        if (frag < 4) {
            v = W1[(8*g + j) * 64 + 16*frag + m];
        } else if (frag < 12) {
            const int s = (frag - 4) >> 2, t = (frag - 4) & 3;
            v = W2[(32*s + 8*g + j) * 64 + 16*t + m];
        } else if (frag < 20) {
            const int s = (frag - 12) >> 2, t = (frag - 12) & 3;
            v = W3[(32*s + 8*g + j) * 64 + 16*t + m];
        } else {
            const int s = frag - 20;
            v = (m < 3) ? W4[(32*s + 8*g + j) * 3 + m] : 0.f;
        }
        wsW[e] = (_Float16)v;
    }
    if (tid < 64) { wsB[tid] = b1[tid]; wsB[64 + tid] = b2[tid]; wsB[128 + tid] = b3[tid]; }
    if (tid >= 64 && tid < 80) { const int r = tid - 64; wsB[192 + r] = (r < 3) ? b4[r] : 0.f; }
    if (tid >= 80 && tid < 96)  wsB[BIAS_FLOATS + (tid - 80)] = nv.n[tid - 80];
}

// ---------------- main fused kernel ----------------
// Round-8 = round-4 body (best: 190 µs) with __launch_bounds__(256,4).
// Cross-round invariant r4-r7: ~190 µs, 0.43 divergent lane-requests/cyc/CU,
// nothing saturated -> MLP starvation of the vector-memory path (waves burst
// 12 loads then stall through MLP+fences; only ~3 blocks/CU resident).
// This round's single change: request 4+ blocks/CU. Body fit in 64 VGPRs under
// a 256 cap, so the 128 cap should not spill (tripwire: WRITE_SIZE >> 13.8 MB).
#define DS_FENCE() __asm__ volatile("s_waitcnt lgkmcnt(0)" ::: "memory")

__global__ __launch_bounds__(256, 4)
void fused_hashnerf_mfma(const float2* __restrict__ X,
                         const float2* __restrict__ table,
                         const uint4* __restrict__ ws,
                         float* __restrict__ out)
{
    __shared__ uint4    sRaw[WS_UINT4];
    __shared__ _Float16 sH[4][16 * HP];

    const int tid = threadIdx.x;
    for (int i = tid; i < WS_UINT4; i += 256) sRaw[i] = ws[i];
    __syncthreads();

    const _Float16* Wl = (const _Float16*)sRaw;
    const float*    Bl = (const float*)(sRaw + (22528 / 16));

    const int wave = tid >> 6, lane = tid & 63;
    const int g = lane >> 4, c = lane & 15;
    _Float16* H = &sH[wave][0];

    float4v b1f[4], b2f[4], b3f[4], b4f;
    #pragma unroll
    for (int t = 0; t < 4; ++t) {
        b1f[t] = *(const float4v*)(Bl +       16*t + 4*g);
        b2f[t] = *(const float4v*)(Bl +  64 + 16*t + 4*g);
        b3f[t] = *(const float4v*)(Bl + 128 + 16*t + 4*g);
    }
    b4f = *(const float4v*)(Bl + 192 + 4*g);

    // per-lane level constants (levels 4g..4g+3)
    float nvq[4]; const float2* tq[4]; float v0x[4], v0y[4];
    #pragma unroll
    for (int q = 0; q < 4; ++q) {
        nvq[q] = Bl[BIAS_FLOATS + 4*g + q];
        tq[q]  = table + (size_t)(4*g + q) * T_;
        const float2 v0 = tq[q][0];          // corner (0,0): point-invariant
        v0x[q] = v0.x; v0y[q] = v0.y;
    }

    const int base_pt = blockIdx.x * 256 + wave * 64;

    for (int it = 0; it < 4; ++it) {
        const int p = base_pt + it * 16 + c;
        const float2 xy = X[p];

        // ---- hash-grid encode: lane (g,c) does levels 4g..4g+3 of point c ----
        // Reference multiplies floor by vertices: corners (0,0),(0,yf),(xf,0),(xf,yf);
        // hash reduces mod 2^18 -> u32 arithmetic exact.
        half8 feat;
        #pragma unroll
        for (int q = 0; q < 4; ++q) {
            const float n = nvq[q];
            const float xs = xy.x * n, ys = xy.y * n;
            const float xf = floorf(xs), yf = floorf(ys);
            const float fx = xs - xf, fy = ys - yf;
            const unsigned xi = (unsigned)(int)xf, yi = (unsigned)(int)yf;
            const unsigned yp = yi * PRIME;
            const float2 v1 = tq[q][yp & TMASK];
            const float2 v2 = tq[q][xi & TMASK];
            const float2 v3 = tq[q][(xi ^ yp) & TMASK];
            const float cx = 1.f - fx, cy = 1.f - fy;
            const float w0 = cx*cy, w1 = cx*fy, w2 = fx*cy, w3 = fx*fy;
            feat[2*q+0] = (_Float16)(w0*v0x[q] + w1*v1.x + w2*v2.x + w3*v3.x);
            feat[2*q+1] = (_Float16)(w0*v0y[q] + w1*v1.y + w2*v2.y + w3*v3.y);
        }

        // ---- L1 ----
        float4v acc[4];
        #pragma unroll
        for (int t = 0; t < 4; ++t) {
            const half8 wf = *(const half8*)(Wl + (t*64 + lane)*8);
            acc[t] = __builtin_amdgcn_mfma_f32_16x16x32_f16(wf, feat, b1f[t], 0, 0, 0);
        }
        #pragma unroll
        for (int t = 0; t < 4; ++t) {
            union { _Float16 h[4]; float2 f2; } u;
            #pragma unroll
            for (int r = 0; r < 4; ++r) {
                const float v = acc[t][r];
                u.h[r] = (_Float16)(v > 0.f ? v : 0.01f * v);
            }
            *(float2*)(H + c*HP + 16*t + 4*g) = u.f2;
        }
        DS_FENCE();

        // ---- L2 ----
        half8 a0 = *(const half8*)(H + c*HP +      8*g);
        half8 a1 = *(const half8*)(H + c*HP + 32 + 8*g);
        float4v acc2[4];
        #pragma unroll
        for (int t = 0; t < 4; ++t) {
            const half8 w0f = *(const half8*)(Wl + ((4 + t)*64 + lane)*8);
            const half8 w1f = *(const half8*)(Wl + ((8 + t)*64 + lane)*8);
            float4v a = __builtin_amdgcn_mfma_f32_16x16x32_f16(w0f, a0, b2f[t], 0, 0, 0);
            acc2[t]   = __builtin_amdgcn_mfma_f32_16x16x32_f16(w1f, a1, a,      0, 0, 0);
        }
        #pragma unroll
        for (int t = 0; t < 4; ++t) {
            union { _Float16 h[4]; float2 f2; } u;
            #pragma unroll
            for (int r = 0; r < 4; ++r) {
                const float v = acc2[t][r];
                u.h[r] = (_Float16)(v > 0.f ? v : 0.01f * v);
            }
            *(float2*)(H + c*HP + 16*t + 4*g) = u.f2;
        }
        DS_FENCE();

        // ---- L3 ----
        a0 = *(const half8*)(H + c*HP +      8*g);
        a1 = *(const half8*)(H + c*HP + 32 + 8*g);
        float4v acc3[4];
        #pragma unroll
        for (int t = 0; t < 4; ++t) {
            const half8 w0f = *(const half8*)(Wl + ((12 + t)*64 + lane)*8);
            const half8 w1f = *(const half8*)(Wl + ((16 + t)*64 + lane)*8);
            float4v a = __builtin_amdgcn_mfma_f32_16x16x32_f16(w0f, a0, b3f[t], 0, 0, 0);
            acc3[t]   = __builtin_amdgcn_mfma_f32_16x16x32_f16(w1f, a1, a,      0, 0, 0);
        }
        #pragma unroll
        for (int t = 0; t < 4; ++t) {
            union { _Float16 h[4]; float2 f2; } u;
            #pragma unroll
            for (int r = 0; r < 4; ++r) {
                const float v = acc3[t][r];
                u.h[r] = (_Float16)(v > 0.f ? v : 0.01f * v);
            }
            *(float2*)(H + c*HP + 16*t + 4*g) = u.f2;
        }
        DS_FENCE();

        // ---- L4 ----
        a0 = *(const half8*)(H + c*HP +      8*g);
        a1 = *(const half8*)(H + c*HP + 32 + 8*g);
        const half8 w40 = *(const half8*)(Wl + (20*64 + lane)*8);
        const half8 w41 = *(const half8*)(Wl + (21*64 + lane)*8);
        float4v o = __builtin_amdgcn_mfma_f32_16x16x32_f16(w40, a0, b4f, 0, 0, 0);
        o         = __builtin_amdgcn_mfma_f32_16x16x32_f16(w41, a1, o,   0, 0, 0);
        if (g == 0) {
            float* op = out + (size_t)3 * p;
            op[0] = fmaxf(o[0], 0.f);
            op[1] = fmaxf(o[1], 0.f);
            op[2] = fmaxf(o[2], 0.f);
        }
    }
}

extern "C" void kernel_launch(void* const* d_in, const int* in_sizes, int n_in,
                              void* d_out, int out_size, void* d_ws, size_t ws_size,
                              hipStream_t stream) {
    const float2* X     = (const float2*)d_in[0];
    const float2* table = (const float2*)d_in[1];
    const float*  W1    = (const float*)d_in[2];
    const float*  b1    = (const float*)d_in[3];
    const float*  W2    = (const float*)d_in[4];
    const float*  b2    = (const float*)d_in[5];
    const float*  W3    = (const float*)d_in[6];
    const float*  b3    = (const float*)d_in[7];
    const float*  W4    = (const float*)d_in[8];
    const float*  b4    = (const float*)d_in[9];
    float* out          = (float*)d_out;

    const int npts = in_sizes[0] / 2;

    // N_l = floor(float32(16 * b^l)), b in double (matches numpy)
    NVals nv;
    const double bg = exp((log(1024.0) - log(16.0)) / 15.0);
    for (int l = 0; l < 16; ++l)
        nv.n[l] = floorf((float)(16.0 * pow(bg, (double)l)));

    _Float16* wsW = (_Float16*)d_ws;
    float*    wsB = (float*)((char*)d_ws + 22528);

    prep_weights<<<1, 256, 0, stream>>>(W1, b1, W2, b2, W3, b3, W4, b4, wsW, wsB, nv);
    fused_hashnerf_mfma<<<npts / 256, 256, 0, stream>>>(X, table, (const uint4*)d_ws, out);
}